// Round 14
// baseline (430.229 us; speedup 1.0000x reference)
//
#include <hip/hip_runtime.h>
#include <hip/hip_fp16.h>

#define N_NODES 100000
#define N_EDGES 3200000
#define NPAD 100096

#define NBLK_P 320
#define SLICE4 (N_EDGES / 4 / NBLK_P)   // 2500 int4 per partition block (exact)
#define NR 3                             // src ranges (slices)
#define NPR 33334                        // nodes per src range (3*33334 >= 100000)
#define KEYN 1024                        // key = (range<<8) | (dst>>9); 768 slots used
#define DB_USED 196                      // dst buckets of 512 nodes
#define RCAP 32                          // register-held bucket cap = 8192 (mean 5461, +37 sigma)
#define NBLKR 25000                      // node-blocks per range (4 nodes each)

using f16x8 = __attribute__((ext_vector_type(8))) _Float16;
using f32x4 = __attribute__((ext_vector_type(4))) float;
using i32x4 = __attribute__((ext_vector_type(4))) int;
using i32x2 = __attribute__((ext_vector_type(2))) int;

// ================= CSR build keyed by (src-range, dst) — no global atomics =================
// packed edge int: src | (dst&511)<<17   (src<2^17, dloc<2^9 -> 26 bits)

__global__ __launch_bounds__(256) void k_coarse_hist(const int4* __restrict__ src4,
                                                     const int4* __restrict__ dst4,
                                                     int* __restrict__ BH) {
    __shared__ int h[KEYN];
    int t = threadIdx.x;
    for (int i = t; i < KEYN; i += 256) h[i] = 0;
    __syncthreads();
    int base = blockIdx.x * SLICE4;
    for (int i = t; i < SLICE4; i += 256) {
        int4 s = src4[base + i];
        int4 d = dst4[base + i];
        atomicAdd(&h[((s.x / NPR) << 8) | (d.x >> 9)], 1);
        atomicAdd(&h[((s.y / NPR) << 8) | (d.y >> 9)], 1);
        atomicAdd(&h[((s.z / NPR) << 8) | (d.z >> 9)], 1);
        atomicAdd(&h[((s.w / NPR) << 8) | (d.w >> 9)], 1);
    }
    __syncthreads();
    for (int i = t; i < KEYN; i += 256) BH[blockIdx.x * KEYN + i] = h[i];
}

__global__ __launch_bounds__(1024) void k_colscan(int* __restrict__ BH,
                                                  int* __restrict__ keyStart,
                                                  int* __restrict__ rsC) {
    __shared__ int s[KEYN];
    int t = threadIdx.x;
    int tot = 0;
    for (int r = 0; r < NBLK_P; ++r) tot += BH[r * KEYN + t];
    s[t] = tot;
    __syncthreads();
    for (int off = 1; off < KEYN; off <<= 1) {
        int v = (t >= off) ? s[t - off] : 0;
        __syncthreads();
        s[t] += v;
        __syncthreads();
    }
    int excl = s[t] - tot;
    keyStart[t] = excl;
    if (t == KEYN - 1) {
        keyStart[KEYN] = s[t];                       // == N_EDGES
        rsC[(long long)NR * N_NODES] = N_EDGES;      // CSR terminator
    }
    int run = excl;
    for (int r = 0; r < NBLK_P; ++r) {
        int v = BH[r * KEYN + t];
        BH[r * KEYN + t] = run;
        run += v;
    }
}

__global__ __launch_bounds__(256) void k_partition(const int4* __restrict__ src4,
                                                   const int4* __restrict__ dst4,
                                                   const int* __restrict__ BH,
                                                   int* __restrict__ edges) {
    __shared__ int cur[KEYN];
    int t = threadIdx.x;
    for (int i = t; i < KEYN; i += 256) cur[i] = BH[blockIdx.x * KEYN + i];
    __syncthreads();
    int base = blockIdx.x * SLICE4;
    for (int i = t; i < SLICE4; i += 256) {
        int4 d = dst4[base + i];
        int4 s = src4[base + i];
        int p;
        p = atomicAdd(&cur[((s.x / NPR) << 8) | (d.x >> 9)], 1);
        edges[p] = s.x | ((d.x & 511) << 17);
        p = atomicAdd(&cur[((s.y / NPR) << 8) | (d.y >> 9)], 1);
        edges[p] = s.y | ((d.y & 511) << 17);
        p = atomicAdd(&cur[((s.z / NPR) << 8) | (d.z >> 9)], 1);
        edges[p] = s.z | ((d.z & 511) << 17);
        p = atomicAdd(&cur[((s.w / NPR) << 8) | (d.w >> 9)], 1);
        edges[p] = s.w | ((d.w & 511) << 17);
    }
}

// per-(range, dst-bucket): register-held fine sort IN PLACE (edges -> csr src order)
__global__ __launch_bounds__(256) void k_fine(int* __restrict__ edges,
                                              const int* __restrict__ keyStart,
                                              int* __restrict__ rsC) {
    __shared__ int h[512];
    __shared__ int pairsc[256];
    __shared__ int offs[512];
    int t = threadIdx.x;
    int db = blockIdx.x;   // 0..195
    int rr = blockIdx.y;   // 0..NR-1
    int key = (rr << 8) | db;
    int beg = keyStart[key], end = keyStart[key + 1];
    int cnt = end - beg;
    int held[RCAP];
    h[t] = 0; h[t + 256] = 0;
    __syncthreads();
#pragma unroll
    for (int c = 0; c < RCAP; ++c) {
        int i = t + c * 256;
        held[c] = (i < cnt) ? edges[beg + i] : -1;
    }
#pragma unroll
    for (int c = 0; c < RCAP; ++c)
        if (held[c] >= 0) atomicAdd(&h[held[c] >> 17], 1);
    __syncthreads();
    int pv = h[2 * t] + h[2 * t + 1];
    pairsc[t] = pv;
    __syncthreads();
    for (int off = 1; off < 256; off <<= 1) {
        int v = (t >= off) ? pairsc[t - off] : 0;
        __syncthreads();
        pairsc[t] += v;
        __syncthreads();
    }
    int e0 = pairsc[t] - pv;
    offs[2 * t] = e0;
    offs[2 * t + 1] = e0 + h[2 * t];
    __syncthreads();
    int n0 = db << 9;
    int nvalid = N_NODES - n0;
    if (nvalid > 512) nvalid = 512;
    long long rb = (long long)rr * N_NODES;
#pragma unroll
    for (int q = 0; q < 2; ++q) {
        int local = t + q * 256;
        if (local < nvalid) rsC[rb + n0 + local] = beg + offs[local];
    }
    __syncthreads();
#pragma unroll
    for (int c = 0; c < RCAP; ++c)
        if (held[c] >= 0) {
            int p = atomicAdd(&offs[held[c] >> 17], 1);
            edges[beg + p] = held[c] & 0x1FFFF;
        }
}

// degree (sum over ranges) -> dinv; fused x -> fp16 dinv-scaled xs
__global__ __launch_bounds__(256) void k_dinv_scale(const int* __restrict__ rsC,
                                                    const float4* __restrict__ x4,
                                                    float* __restrict__ dinv,
                                                    int2* __restrict__ xs2) {
    __shared__ float dl[64];
    int t = threadIdx.x;
    int nb = blockIdx.x * 64;
    if (t < 64) {
        int n = nb + t;
        if (n < N_NODES) {
            int deg = 0;
#pragma unroll
            for (int r = 0; r < NR; ++r) {
                long long rb = (long long)r * N_NODES + n;
                deg += rsC[rb + 1] - rsC[rb];
            }
            float dv = rsqrtf((float)(deg + 1));
            dl[t] = dv;
            dinv[n] = dv;
        }
    }
    __syncthreads();
    for (int i = t; i < 64 * 16; i += 256) {
        int local = i >> 4, q = i & 15;
        int n = nb + local;
        if (n < N_NODES) {
            float d = dl[local];
            float4 v = x4[(long long)n * 16 + q];
            __half2 lo = __float22half2_rn(make_float2(v.x * d, v.y * d));
            __half2 hi = __float22half2_rn(make_float2(v.z * d, v.w * d));
            xs2[(long long)n * 16 + q] = make_int2(*(int*)&lo, *(int*)&hi);
        }
    }
}

// ---------------- soft-phased gather v2: 16 lanes/row x 4 edges, zero inner DS ----------------
// range slowest in bid -> concurrent blocks share one ~4.3MB slice (L2-resident)

__global__ __launch_bounds__(256) void k_gather_phase(
    const int* __restrict__ rsC, const int* __restrict__ csr,
    const int2* __restrict__ feat2, i32x2* __restrict__ part2)
{
    int bid = blockIdx.x;
    int r = bid / NBLKR;                                   // soft phase lock
    int node = (bid - r * NBLKR) * 4 + (threadIdx.x >> 6); // N divisible by 4
    int lane = threadIdx.x & 63;
    int q = lane & 15;    // 8B slot (4 halves) within the 128B row
    int eg = lane >> 4;   // 0..3: edge slot
    long long rb = (long long)r * N_NODES;
    int beg = rsC[rb + node];
    int deg = rsC[rb + node + 1] - beg;
    float a0 = 0.f, a1 = 0.f, a2 = 0.f, a3 = 0.f;
    for (int base = 0; base < deg; base += 8) {
#pragma unroll
        for (int u = 0; u < 2; ++u) {
            int idx = base + (u << 2) + eg;
            if (idx < deg) {
                int s = __builtin_nontemporal_load(&csr[beg + idx]);  // 16-lane broadcast
                int2 v = feat2[(long long)s * 16 + q];                // cached (L2 slice)
                float2 fa = __half22float2(*(__half2*)&v.x);
                float2 fb = __half22float2(*(__half2*)&v.y);
                a0 += fa.x; a1 += fa.y; a2 += fb.x; a3 += fb.y;
            }
        }
    }
    // pack to fp16 pairs, 2-level tree over the 4 edge-groups (4 shfl + 4 hadd2)
    __half2 p0 = __float22half2_rn(make_float2(a0, a1));
    __half2 p1 = __float22half2_rn(make_float2(a2, a3));
    int d0 = *(int*)&p0, d1 = *(int*)&p1;
    int o0 = __shfl_xor(d0, 16), o1 = __shfl_xor(d1, 16);
    p0 = __hadd2(p0, *(__half2*)&o0);
    p1 = __hadd2(p1, *(__half2*)&o1);
    d0 = *(int*)&p0; d1 = *(int*)&p1;
    o0 = __shfl_xor(d0, 32); o1 = __shfl_xor(d1, 32);
    p0 = __hadd2(p0, *(__half2*)&o0);
    p1 = __hadd2(p1, *(__half2*)&o1);
    if (eg == 0) {
        i32x2 o = {*(int*)&p0, *(int*)&p1};
        __builtin_nontemporal_store(o, &part2[(rb + node) * 16 + q]);
    }
}

// ---------------- MFMA fused GEMM: A = dinv*(xs + sum_r part); P = fp16(dinv*(relu(A@W1+b1)@W2)) ----------------

#define GEMM_GROUPS 2
__global__ __launch_bounds__(256) void k_mfma_gemm(
    const f16x8* __restrict__ xs8, const f16x8* __restrict__ part8,
    const float* __restrict__ W1, const float* __restrict__ b1g,
    const float* __restrict__ W2, const float* __restrict__ dinv,
    _Float16* __restrict__ P)
{
    __shared__ _Float16 sW1T[128][72];
    __shared__ _Float16 sW2T[64][136];
    __shared__ _Float16 sH[4][16][136];
    int tid = threadIdx.x;
    for (int i = tid; i < 64 * 128; i += 256) {
        int k = i >> 7, c = i & 127;
        sW1T[c][k] = (_Float16)W1[i];
    }
    for (int i = tid; i < 128 * 64; i += 256) {
        int k = i >> 6, c = i & 63;
        sW2T[c][k] = (_Float16)W2[i];
    }
    __syncthreads();
    int w = tid >> 6;
    int l = tid & 63;
    int lr = l & 15;
    int lk = l >> 4;

    for (int g = 0; g < GEMM_GROUPS; ++g) {
        int base = blockIdx.x * (64 * GEMM_GROUPS) + (w * GEMM_GROUPS + g) * 16;
        int row = base + lr;
        f16x8 a0 = (f16x8)(_Float16)0, a1 = (f16x8)(_Float16)0;
        if (row < N_NODES) {
            float dv = dinv[row];
            float f0[8], f1[8];
            f16x8 v0 = xs8[(long long)row * 8 + lk];
            f16x8 v1 = xs8[(long long)row * 8 + 4 + lk];
#pragma unroll
            for (int i = 0; i < 8; ++i) { f0[i] = (float)v0[i]; f1[i] = (float)v1[i]; }
#pragma unroll
            for (int r = 0; r < NR; ++r) {
                f16x8 p0 = part8[((long long)r * N_NODES + row) * 8 + lk];
                f16x8 p1 = part8[((long long)r * N_NODES + row) * 8 + 4 + lk];
#pragma unroll
                for (int i = 0; i < 8; ++i) { f0[i] += (float)p0[i]; f1[i] += (float)p1[i]; }
            }
#pragma unroll
            for (int i = 0; i < 8; ++i) {
                a0[i] = (_Float16)(dv * f0[i]);
                a1[i] = (_Float16)(dv * f1[i]);
            }
        }
        for (int nt = 0; nt < 8; ++nt) {
            f32x4 acc = {0.f, 0.f, 0.f, 0.f};
            f16x8 bf0 = *(const f16x8*)&sW1T[nt * 16 + lr][lk * 8];
            f16x8 bf1 = *(const f16x8*)&sW1T[nt * 16 + lr][32 + lk * 8];
            acc = __builtin_amdgcn_mfma_f32_16x16x32_f16(a0, bf0, acc, 0, 0, 0);
            acc = __builtin_amdgcn_mfma_f32_16x16x32_f16(a1, bf1, acc, 0, 0, 0);
            float bb = b1g[nt * 16 + lr];
#pragma unroll
            for (int r = 0; r < 4; ++r)
                sH[w][4 * lk + r][nt * 16 + lr] = (_Float16)fmaxf(acc[r] + bb, 0.f);
        }
        f16x8 ha[4];
#pragma unroll
        for (int ks = 0; ks < 4; ++ks)
            ha[ks] = *(const f16x8*)&sH[w][lr][ks * 32 + lk * 8];
        float dv2[4];
#pragma unroll
        for (int r = 0; r < 4; ++r) dv2[r] = dinv[base + 4 * lk + r];
        for (int nt = 0; nt < 4; ++nt) {
            f32x4 acc = {0.f, 0.f, 0.f, 0.f};
#pragma unroll
            for (int ks = 0; ks < 4; ++ks) {
                f16x8 bf = *(const f16x8*)&sW2T[nt * 16 + lr][ks * 32 + lk * 8];
                acc = __builtin_amdgcn_mfma_f32_16x16x32_f16(ha[ks], bf, acc, 0, 0, 0);
            }
#pragma unroll
            for (int r = 0; r < 4; ++r) {
                int rr = base + 4 * lk + r;
                if (rr < N_NODES)
                    P[(long long)rr * 64 + nt * 16 + lr] = (_Float16)(dv2[r] * acc[r]);
            }
        }
    }
}

// ---------------- layer-2 reduce: out = dinv*(p2_self + sum_r part) + b2 ----------------

__device__ __forceinline__ void unpack_add8(int4 v, float* f) {
    float2 a = __half22float2(*(__half2*)&v.x);
    float2 b = __half22float2(*(__half2*)&v.y);
    float2 c = __half22float2(*(__half2*)&v.z);
    float2 d = __half22float2(*(__half2*)&v.w);
    f[0] += a.x; f[1] += a.y; f[2] += b.x; f[3] += b.y;
    f[4] += c.x; f[5] += c.y; f[6] += d.x; f[7] += d.y;
}

__global__ __launch_bounds__(256) void k_reduce_out(
    const int4* __restrict__ p2h, const int4* __restrict__ part,
    const float* __restrict__ dinv, const float4* __restrict__ bias4,
    float4* __restrict__ out4)
{
    int t = threadIdx.x;
    int node = blockIdx.x * 32 + (t >> 3);
    if (node >= N_NODES) return;
    int q = t & 7;
    float f[8];
#pragma unroll
    for (int k = 0; k < 8; ++k) f[k] = 0.f;
    unpack_add8(p2h[((long long)node << 3) + q], f);
#pragma unroll
    for (int r = 0; r < NR; ++r)
        unpack_add8(part[((long long)r * N_NODES + node) * 8 + q], f);
    float d = dinv[node];
    float4 b0 = bias4[q * 2];
    float4 b1 = bias4[q * 2 + 1];
    f32x4 o0 = {d * f[0] + b0.x, d * f[1] + b0.y, d * f[2] + b0.z, d * f[3] + b0.w};
    f32x4 o1 = {d * f[4] + b1.x, d * f[5] + b1.y, d * f[6] + b1.z, d * f[7] + b1.w};
    __builtin_nontemporal_store(o0, (f32x4*)&out4[(long long)node * 16 + q * 2]);
    __builtin_nontemporal_store(o1, (f32x4*)&out4[(long long)node * 16 + q * 2 + 1]);
}

// ---------------- launch ----------------

extern "C" void kernel_launch(void* const* d_in, const int* in_sizes, int n_in,
                              void* d_out, int out_size, void* d_ws, size_t ws_size,
                              hipStream_t stream) {
    const float* x  = (const float*)d_in[0];
    const int*   ei = (const int*)d_in[1];
    const float* W1 = (const float*)d_in[2];
    const float* b1 = (const float*)d_in[3];
    const float* W2 = (const float*)d_in[4];
    const float* b2 = (const float*)d_in[5];
    float* out = (float*)d_out;

    const int* srcE = ei;            // edge_index[0]
    const int* dstE = ei + N_EDGES;  // edge_index[1]

    // workspace layout (~66.9 MB; known-good ws >= 77.2 MB from R1)
    char* w = (char*)d_ws;
    int*   BH       = (int*)w;   w += sizeof(int) * NBLK_P * KEYN;
    int*   keyStart = (int*)w;   w += sizeof(int) * (KEYN + 1);
    int*   rsC      = (int*)w;   w += sizeof(int) * (NR * N_NODES + 8);
    float* dinv     = (float*)w; w += sizeof(float) * (N_NODES + 128);
    int*   edges    = (int*)w;   w += sizeof(int) * N_EDGES;
    char*  xsbuf    = w;         w += 128 * (size_t)N_NODES;
    char*  partbuf  = w;         w += 128 * (size_t)N_NODES * NR;

    int2* xs2  = (int2*)xsbuf;
    int4* part = (int4*)partbuf;
    _Float16* p2 = (_Float16*)xsbuf;

    // CSR build keyed by (src-range, dst)
    k_coarse_hist<<<NBLK_P, 256, 0, stream>>>((const int4*)srcE, (const int4*)dstE, BH);
    k_colscan<<<1, 1024, 0, stream>>>(BH, keyStart, rsC);
    k_partition<<<NBLK_P, 256, 0, stream>>>((const int4*)srcE, (const int4*)dstE, BH, edges);
    k_fine<<<dim3(DB_USED, NR), 256, 0, stream>>>(edges, keyStart, rsC);
    k_dinv_scale<<<(N_NODES + 63) / 64, 256, 0, stream>>>(rsC, (const float4*)x, dinv, xs2);

    // layer 1: soft-phased partial gather; GEMM folds the partial-sum + dinv into A-staging
    k_gather_phase<<<NR * NBLKR, 256, 0, stream>>>(rsC, edges, (const int2*)xs2,
                                                   (i32x2*)partbuf);
    k_mfma_gemm<<<NPAD / 128, 256, 0, stream>>>((const f16x8*)xsbuf, (const f16x8*)partbuf,
                                                W1, b1, W2, dinv, p2);

    // layer 2: soft-phased partial gather of p2; reduce writes out (+b2)
    k_gather_phase<<<NR * NBLKR, 256, 0, stream>>>(rsC, edges, (const int2*)p2,
                                                   (i32x2*)partbuf);
    k_reduce_out<<<(N_NODES + 31) / 32, 256, 0, stream>>>((const int4*)p2, part, dinv,
                                                          (const float4*)b2, (float4*)out);
}

// Round 15
// 281.607 us; speedup vs baseline: 1.5278x; 1.5278x over previous
//
#include <hip/hip_runtime.h>
#include <hip/hip_fp16.h>

#define N_NODES 100000
#define N_EDGES 3200000
#define NPAD 100096   // row-padded node count (multiple of 128)

#define NBLK_P 320
#define SLICE4 (N_EDGES / 4 / NBLK_P)       // 2500 int4 per partition block (exact)
#define NBKT 512
#define BSHIFT 8                             // 256 nodes per coarse bucket
#define NBKT_USED ((N_NODES + 255) / 256)    // 391
#define EL_CAP 12288                         // LDS edge cache (48 KB); mean bucket = 8184

using f16x8 = __attribute__((ext_vector_type(8))) _Float16;
using f32x4 = __attribute__((ext_vector_type(4))) float;
using i32x4 = __attribute__((ext_vector_type(4))) int;

// ================= CSR build: two-level counting sort by dst (no global atomics) =================
// packed edge int: src | (dst&255)<<17   (src<2^17, dloc<2^8)

__global__ __launch_bounds__(256) void k_coarse_hist(const int4* __restrict__ dst4,
                                                     int* __restrict__ blockHist) {
    __shared__ int h[NBKT];
    int t = threadIdx.x;
    h[t] = 0; h[t + 256] = 0;
    __syncthreads();
    int base = blockIdx.x * SLICE4;
    for (int i = t; i < SLICE4; i += 256) {
        int4 d = dst4[base + i];
        atomicAdd(&h[d.x >> BSHIFT], 1);
        atomicAdd(&h[d.y >> BSHIFT], 1);
        atomicAdd(&h[d.z >> BSHIFT], 1);
        atomicAdd(&h[d.w >> BSHIFT], 1);
    }
    __syncthreads();
    blockHist[blockIdx.x * NBKT + t] = h[t];
    blockHist[blockIdx.x * NBKT + t + 256] = h[t + 256];
}

__global__ __launch_bounds__(1024) void k_colscan(int* __restrict__ blockHist,
                                                  int* __restrict__ coarseStart) {
    __shared__ int part[2][NBKT];
    __shared__ int s[NBKT];
    __shared__ int totA[NBKT];
    int tid = threadIdx.x;
    int b = tid & 511, q = tid >> 9;
    const int QR = NBLK_P / 2;  // 160
    int sum = 0;
    for (int r = q * QR; r < (q + 1) * QR; ++r) sum += blockHist[r * NBKT + b];
    part[q][b] = sum;
    __syncthreads();
    if (q == 0) {
        int tot = part[0][b] + part[1][b];
        s[b] = tot;
        totA[b] = tot;
    }
    __syncthreads();
    for (int off = 1; off < NBKT; off <<= 1) {
        int v = 0;
        if (q == 0 && b >= off) v = s[b - off];
        __syncthreads();
        if (q == 0) s[b] += v;
        __syncthreads();
    }
    int excl = s[b] - totA[b];
    if (q == 0) {
        coarseStart[b] = excl;
        if (b == 0) coarseStart[NBKT] = N_EDGES;
    }
    int run = excl;
    if (q == 1) run += part[0][b];
    for (int r = q * QR; r < (q + 1) * QR; ++r) {
        int v = blockHist[r * NBKT + b];
        blockHist[r * NBKT + b] = run;
        run += v;
    }
}

__global__ __launch_bounds__(256) void k_partition(const int4* __restrict__ src4,
                                                   const int4* __restrict__ dst4,
                                                   const int* __restrict__ blockHist,
                                                   int* __restrict__ sorted) {
    __shared__ int cur[NBKT];
    int t = threadIdx.x;
    cur[t] = blockHist[blockIdx.x * NBKT + t];
    cur[t + 256] = blockHist[blockIdx.x * NBKT + t + 256];
    __syncthreads();
    int base = blockIdx.x * SLICE4;
    for (int i = t; i < SLICE4; i += 256) {
        int4 d = dst4[base + i];
        int4 s = src4[base + i];
        int p;
        p = atomicAdd(&cur[d.x >> BSHIFT], 1); sorted[p] = s.x | ((d.x & 255) << 17);
        p = atomicAdd(&cur[d.y >> BSHIFT], 1); sorted[p] = s.y | ((d.y & 255) << 17);
        p = atomicAdd(&cur[d.z >> BSHIFT], 1); sorted[p] = s.z | ((d.z & 255) << 17);
        p = atomicAdd(&cur[d.w >> BSHIFT], 1); sorted[p] = s.w | ((d.w & 255) << 17);
    }
}

// per-bucket: fine hist + scan -> rowstart/dinv, scatter srcs, fused x->fp16 scale
__global__ __launch_bounds__(256) void k_fine(const int* __restrict__ sorted,
                                              const int* __restrict__ coarseStart,
                                              const float4* __restrict__ x4,
                                              int* __restrict__ rowstart,
                                              float* __restrict__ dinvg,
                                              int* __restrict__ csr_src,
                                              int2* __restrict__ xs2) {
    __shared__ int eL[EL_CAP];
    __shared__ int h[256];
    __shared__ int pairsc[256];
    __shared__ int offs[256];
    __shared__ float dloc[256];
    int t = threadIdx.x;
    int bkt = blockIdx.x;
    int beg = coarseStart[bkt], end = coarseStart[bkt + 1];
    int cnt = end - beg;
    bool inLds = (cnt <= EL_CAP);
    h[t] = 0;
    __syncthreads();
    if (inLds) {
        for (int i = t; i < cnt; i += 256) eL[i] = sorted[beg + i];
        __syncthreads();
        for (int i = t; i < cnt; i += 256) atomicAdd(&h[eL[i] >> 17], 1);
    } else {
        for (int i = beg + t; i < end; i += 256) atomicAdd(&h[sorted[i] >> 17], 1);
    }
    __syncthreads();
    int pv = h[t];
    pairsc[t] = pv;
    __syncthreads();
    for (int off = 1; off < 256; off <<= 1) {
        int v = (t >= off) ? pairsc[t - off] : 0;
        __syncthreads();
        pairsc[t] += v;
        __syncthreads();
    }
    int e0 = pairsc[t] - pv;  // exclusive
    offs[t] = e0;
    int n0 = bkt << BSHIFT;
    int nvalid = N_NODES - n0;
    if (nvalid > 256) nvalid = 256;
    if (t < nvalid) {
        rowstart[n0 + t] = beg + e0;
        float dv = rsqrtf((float)(pv + 1));
        dloc[t] = dv;
        dinvg[n0 + t] = dv;
    }
    if (bkt == 0 && t == 0) rowstart[N_NODES] = N_EDGES;
    __syncthreads();
    if (inLds) {
        for (int i = t; i < cnt; i += 256) {
            int pk = eL[i];
            int p = atomicAdd(&offs[pk >> 17], 1);
            csr_src[beg + p] = pk & 0x1FFFF;
        }
    } else {
        for (int i = beg + t; i < end; i += 256) {
            int pk = sorted[i];
            int p = atomicAdd(&offs[pk >> 17], 1);
            csr_src[beg + p] = pk & 0x1FFFF;
        }
    }
    // fused scale: xs[row] = fp16(dinv[row] * x[row]) for this bucket's rows
    for (int i = t; i < nvalid * 16; i += 256) {
        int local = i >> 4;
        int qq = i & 15;
        float d = dloc[local];
        float4 v = x4[(long long)(n0 + local) * 16 + qq];
        __half2 lo = __float22half2_rn(make_float2(v.x * d, v.y * d));
        __half2 hi = __float22half2_rn(make_float2(v.z * d, v.w * d));
        xs2[(long long)(n0 + local) * 16 + qq] = make_int2(*(int*)&lo, *(int*)&hi);
    }
}

// ---------------- full-row gather (fp16 rows = 128B = one line) ----------------
// 8 lanes x 16B per row, 8 edge-rows in flight; inner loop batched 32 edges
// (4 shfl + 4 independent loads issued before the adds -> 4 row-requests in flight)

__device__ __forceinline__ void acc_add8(int4 v, float acc[8]) {
    float2 f0 = __half22float2(*(__half2*)&v.x);
    float2 f1 = __half22float2(*(__half2*)&v.y);
    float2 f2 = __half22float2(*(__half2*)&v.z);
    float2 f3 = __half22float2(*(__half2*)&v.w);
    acc[0] += f0.x; acc[1] += f0.y; acc[2] += f1.x; acc[3] += f1.y;
    acc[4] += f2.x; acc[5] += f2.y; acc[6] += f3.x; acc[7] += f3.y;
}

__device__ __forceinline__ void gather_core(
    const int* __restrict__ rowstart, const int* __restrict__ csr_src,
    const int4* __restrict__ xs16, int node, int lane, float acc[8])
{
    int qlane = lane & 7;
    int egrp = lane >> 3;
    int beg = rowstart[node];
    int deg = rowstart[node + 1] - beg;
#pragma unroll
    for (int k = 0; k < 8; ++k) acc[k] = 0.f;
    if (egrp == 0) {  // self loop (pre-scaled)
        acc_add8(xs16[((long long)node << 3) + qlane], acc);
    }
    for (int base = 0; base < deg; base += 64) {
        int rem = deg - base;
        if (rem > 64) rem = 64;
        int mye = (lane < rem) ? __builtin_nontemporal_load(&csr_src[beg + base + lane]) : 0;
        int j = 0;
        // batched: 32 edges per step, 4 independent row-loads in flight
        for (; j + 32 <= rem; j += 32) {
            int s0 = __shfl(mye, j + egrp);
            int s1 = __shfl(mye, j + 8 + egrp);
            int s2 = __shfl(mye, j + 16 + egrp);
            int s3 = __shfl(mye, j + 24 + egrp);
            int4 v0 = xs16[((long long)s0 << 3) + qlane];
            int4 v1 = xs16[((long long)s1 << 3) + qlane];
            int4 v2 = xs16[((long long)s2 << 3) + qlane];
            int4 v3 = xs16[((long long)s3 << 3) + qlane];
            acc_add8(v0, acc);
            acc_add8(v1, acc);
            acc_add8(v2, acc);
            acc_add8(v3, acc);
        }
        for (; j < rem; j += 8) {
            int eidx = j + egrp;
            int s = __shfl(mye, eidx);
            if (eidx < rem) acc_add8(xs16[((long long)s << 3) + qlane], acc);
        }
    }
#pragma unroll
    for (int k = 0; k < 8; ++k) {
        acc[k] += __shfl_xor(acc[k], 8);
        acc[k] += __shfl_xor(acc[k], 16);
        acc[k] += __shfl_xor(acc[k], 32);
    }
}

// layer-1: out fp16, dinv-scaled, no bias (NT store via ext_vector)
__global__ __launch_bounds__(256) void k_gather_h16(
    const int* __restrict__ rowstart, const int* __restrict__ csr_src,
    const float* __restrict__ dinv, const int4* __restrict__ xs16,
    int4* __restrict__ aggh)
{
    int node = blockIdx.x * 4 + (threadIdx.x >> 6);
    if (node >= N_NODES) return;
    int lane = threadIdx.x & 63;
    float acc[8];
    gather_core(rowstart, csr_src, xs16, node, lane, acc);
    if ((lane >> 3) == 0) {
        float d = dinv[node];
        __half2 h0 = __float22half2_rn(make_float2(d * acc[0], d * acc[1]));
        __half2 h1 = __float22half2_rn(make_float2(d * acc[2], d * acc[3]));
        __half2 h2 = __float22half2_rn(make_float2(d * acc[4], d * acc[5]));
        __half2 h3 = __float22half2_rn(make_float2(d * acc[6], d * acc[7]));
        i32x4 o = {*(int*)&h0, *(int*)&h1, *(int*)&h2, *(int*)&h3};
        __builtin_nontemporal_store(o, (i32x4*)&aggh[((long long)node << 3) + (lane & 7)]);
    }
}

// layer-2: out f32 with dinv scale + bias (NT store via ext_vector)
__global__ __launch_bounds__(256) void k_gather_f32(
    const int* __restrict__ rowstart, const int* __restrict__ csr_src,
    const float* __restrict__ dinv, const int4* __restrict__ xs16,
    const float4* __restrict__ bias4, float4* __restrict__ out4)
{
    int node = blockIdx.x * 4 + (threadIdx.x >> 6);
    if (node >= N_NODES) return;
    int lane = threadIdx.x & 63;
    float acc[8];
    gather_core(rowstart, csr_src, xs16, node, lane, acc);
    int qlane = lane & 7;
    if ((lane >> 3) == 0) {
        float d = dinv[node];
        float4 b0 = bias4[qlane * 2];
        float4 b1 = bias4[qlane * 2 + 1];
        f32x4 o0 = {d * acc[0] + b0.x, d * acc[1] + b0.y, d * acc[2] + b0.z, d * acc[3] + b0.w};
        f32x4 o1 = {d * acc[4] + b1.x, d * acc[5] + b1.y, d * acc[6] + b1.z, d * acc[7] + b1.w};
        __builtin_nontemporal_store(o0, (f32x4*)&out4[(long long)node * 16 + qlane * 2]);
        __builtin_nontemporal_store(o1, (f32x4*)&out4[(long long)node * 16 + qlane * 2 + 1]);
    }
}

// ---------------- MFMA fused GEMM: P = fp16(dinv * (relu(A@W1 + b1) @ W2)) ----------------

#define GEMM_GROUPS 2
__global__ __launch_bounds__(256) void k_mfma_gemm(
    const f16x8* __restrict__ aggh8, const float* __restrict__ W1,
    const float* __restrict__ b1g, const float* __restrict__ W2,
    const float* __restrict__ dinv, _Float16* __restrict__ P)
{
    __shared__ _Float16 sW1T[128][72];
    __shared__ _Float16 sW2T[64][136];
    __shared__ _Float16 sH[4][16][136];
    int tid = threadIdx.x;
    for (int i = tid; i < 64 * 128; i += 256) {
        int k = i >> 7, c = i & 127;
        sW1T[c][k] = (_Float16)W1[i];
    }
    for (int i = tid; i < 128 * 64; i += 256) {
        int k = i >> 6, c = i & 63;
        sW2T[c][k] = (_Float16)W2[i];
    }
    __syncthreads();
    int w = tid >> 6;
    int l = tid & 63;
    int lr = l & 15;
    int lk = l >> 4;

    for (int g = 0; g < GEMM_GROUPS; ++g) {
        int base = blockIdx.x * (64 * GEMM_GROUPS) + (w * GEMM_GROUPS + g) * 16;
        int row = base + lr;
        f16x8 a0 = aggh8[(long long)row * 8 + lk];
        f16x8 a1 = aggh8[(long long)row * 8 + 4 + lk];
        for (int nt = 0; nt < 8; ++nt) {
            f32x4 acc = {0.f, 0.f, 0.f, 0.f};
            f16x8 bf0 = *(const f16x8*)&sW1T[nt * 16 + lr][lk * 8];
            f16x8 bf1 = *(const f16x8*)&sW1T[nt * 16 + lr][32 + lk * 8];
            acc = __builtin_amdgcn_mfma_f32_16x16x32_f16(a0, bf0, acc, 0, 0, 0);
            acc = __builtin_amdgcn_mfma_f32_16x16x32_f16(a1, bf1, acc, 0, 0, 0);
            float bb = b1g[nt * 16 + lr];
#pragma unroll
            for (int r = 0; r < 4; ++r)
                sH[w][4 * lk + r][nt * 16 + lr] = (_Float16)fmaxf(acc[r] + bb, 0.f);
        }
        f16x8 ha[4];
#pragma unroll
        for (int ks = 0; ks < 4; ++ks)
            ha[ks] = *(const f16x8*)&sH[w][lr][ks * 32 + lk * 8];
        float dv[4];
#pragma unroll
        for (int r = 0; r < 4; ++r) dv[r] = dinv[base + 4 * lk + r];
        for (int nt = 0; nt < 4; ++nt) {
            f32x4 acc = {0.f, 0.f, 0.f, 0.f};
#pragma unroll
            for (int ks = 0; ks < 4; ++ks) {
                f16x8 bf = *(const f16x8*)&sW2T[nt * 16 + lr][ks * 32 + lk * 8];
                acc = __builtin_amdgcn_mfma_f32_16x16x32_f16(ha[ks], bf, acc, 0, 0, 0);
            }
#pragma unroll
            for (int r = 0; r < 4; ++r) {
                int rr = base + 4 * lk + r;
                if (rr < N_NODES)
                    P[(long long)rr * 64 + nt * 16 + lr] = (_Float16)(dv[r] * acc[r]);
            }
        }
    }
}

// ---------------- launch ----------------

extern "C" void kernel_launch(void* const* d_in, const int* in_sizes, int n_in,
                              void* d_out, int out_size, void* d_ws, size_t ws_size,
                              hipStream_t stream) {
    const float* x  = (const float*)d_in[0];
    const int*   ei = (const int*)d_in[1];
    const float* W1 = (const float*)d_in[2];
    const float* b1 = (const float*)d_in[3];
    const float* W2 = (const float*)d_in[4];
    const float* b2 = (const float*)d_in[5];
    float* out = (float*)d_out;

    const int* srcE = ei;            // edge_index[0]
    const int* dstE = ei + N_EDGES;  // edge_index[1]

    // workspace layout
    char* w = (char*)d_ws;
    int*   blockHist   = (int*)w;   w += sizeof(int) * NBLK_P * NBKT;
    int*   coarseStart = (int*)w;   w += sizeof(int) * (NBKT + 1);
    int*   rowstart    = (int*)w;   w += sizeof(int) * (N_NODES + 8);
    float* dinv        = (float*)w; w += sizeof(float) * (NPAD + 128);
    int*   csr_src     = (int*)w;   w += sizeof(int) * N_EDGES;
    char*  xsbuf       = w;         w += 128 * (size_t)NPAD;   // [N][64] fp16
    // union: sorted (E ints = 12.8MB) dies before aggh (NPAD rows fp16) is written
    char*  ubuf        = w;         w += 128 * (size_t)NPAD;
    int*   sorted = (int*)ubuf;
    int4*  aggh   = (int4*)ubuf;
    int4*  xs     = (int4*)xsbuf;
    _Float16* p2  = (_Float16*)xsbuf;  // xs dead after layer-1 gather; reuse for fp16 p2

    // CSR build (no global atomics) + fused dinv/scale
    k_coarse_hist<<<NBLK_P, 256, 0, stream>>>((const int4*)dstE, blockHist);
    k_colscan<<<1, 1024, 0, stream>>>(blockHist, coarseStart);
    k_partition<<<NBLK_P, 256, 0, stream>>>((const int4*)srcE, (const int4*)dstE,
                                            blockHist, sorted);
    k_fine<<<NBKT_USED, 256, 0, stream>>>(sorted, coarseStart, (const float4*)x,
                                          rowstart, dinv, csr_src, (int2*)xsbuf);

    // layer 1: full-row gather (fp16 out), then MFMA fused GEMMs -> p2 (fp16, dinv-scaled)
    k_gather_h16<<<(N_NODES + 3) / 4, 256, 0, stream>>>(rowstart, csr_src, dinv, xs, aggh);
    k_mfma_gemm<<<NPAD / 128, 256, 0, stream>>>((const f16x8*)aggh, W1, b1, W2, dinv, p2);

    // layer 2: full-row gather into out (+b2)
    k_gather_f32<<<(N_NODES + 3) / 4, 256, 0, stream>>>(rowstart, csr_src, dinv,
                                                        (const int4*)p2,
                                                        (const float4*)b2, (float4*)out);
}